// Round 5
// baseline (415.276 us; speedup 1.0000x reference)
//
#include <hip/hip_runtime.h>
#include <hip/hip_bf16.h>

#define HID1 16
#define NHEAD1 12
#define F1 (HID1*NHEAD1)   // 192
#define HID2 8
#define NHEAD2 8
#define F2 (HID2*NHEAD2)   // 64
#define NUM_FEA 213
#define NEG_SLOPE 0.2f
#define KP 224             // layer-1 K padded to 7*32 for MFMA
#define KP2 192            // layer-2 K (already 6*32)
#define LDK 40             // LDS k-stride (bf16 elems): 80B -> bank stride 20, 2-way max (free)
#define MROWS 128          // gemm block row tile

typedef __attribute__((ext_vector_type(8))) __bf16 bf16x8;
typedef __attribute__((ext_vector_type(4))) float floatx4;
typedef unsigned short ushort_t;

static __device__ __forceinline__ unsigned short f2bf(float f) {
    unsigned u = __float_as_uint(f);
    unsigned r = (u + 0x7fffu + ((u >> 16) & 1u)) >> 16;   // RNE
    return (unsigned short)r;
}
static __device__ __forceinline__ float bf2f(unsigned short u) {
    return __uint_as_float(((unsigned)u) << 16);
}
static __device__ __forceinline__ float lrelu(float e) {
    return e > 0.f ? e : NEG_SLOPE * e;
}

// ---------------- CSR build ----------------

__global__ void deg_kernel(const int* __restrict__ ei, int* __restrict__ cnt, int E, int Etot) {
    int e = blockIdx.x * blockDim.x + threadIdx.x;
    if (e >= Etot) return;
    int d = (e < E) ? ei[E + e] : (e - E);
    atomicAdd(&cnt[d], 1);
}

__global__ __launch_bounds__(256) void scan1_kernel(const int* __restrict__ cnt,
                                                    int* __restrict__ part,
                                                    int* __restrict__ bsum, int N) {
    __shared__ int tmp[256];
    int tid = threadIdx.x;
    int i = blockIdx.x * 256 + tid;
    int v = (i < N) ? cnt[i] : 0;
    tmp[tid] = v;
    __syncthreads();
    for (int off = 1; off < 256; off <<= 1) {
        int add = (tid >= off) ? tmp[tid - off] : 0;
        __syncthreads();
        tmp[tid] += add;
        __syncthreads();
    }
    if (i < N) part[i] = tmp[tid] - v;
    if (tid == 255) bsum[blockIdx.x] = tmp[255];
}

__global__ __launch_bounds__(256) void scan2_kernel(int* __restrict__ bsum, int nb) {
    __shared__ int tmp[256];
    int tid = threadIdx.x;
    int v = (tid < nb) ? bsum[tid] : 0;
    tmp[tid] = v;
    __syncthreads();
    for (int off = 1; off < 256; off <<= 1) {
        int add = (tid >= off) ? tmp[tid - off] : 0;
        __syncthreads();
        tmp[tid] += add;
        __syncthreads();
    }
    if (tid < nb) bsum[tid] = tmp[tid] - v;
}

__global__ __launch_bounds__(256) void scan3_kernel(const int* __restrict__ part,
                                                    const int* __restrict__ bsum,
                                                    int* __restrict__ rowstart, int N, int Etot) {
    int i = blockIdx.x * 256 + threadIdx.x;
    if (i < N) rowstart[i] = part[i] + bsum[blockIdx.x];
    if (i == 0) rowstart[N] = Etot;
}

__global__ void fill_kernel(const int* __restrict__ ei, const int* __restrict__ rowstart,
                            int* __restrict__ cnt2, int* __restrict__ esrc,
                            int* __restrict__ edst, int E, int Etot) {
    int e = blockIdx.x * blockDim.x + threadIdx.x;
    if (e >= Etot) return;
    int s, d;
    if (e < E) { s = ei[e]; d = ei[E + e]; } else { s = e - E; d = s; }
    int pos = rowstart[d] + atomicAdd(&cnt2[d], 1);
    esrc[pos] = s;
    edst[pos] = d;
}

// ---------------- bf16 conversion ----------------

__global__ void convX_kernel(const float* __restrict__ X, ushort_t* __restrict__ Xbf,
                             int N, long total) {
    long idx = (long)blockIdx.x * blockDim.x + threadIdx.x;
    if (idx >= total) return;
    int r = (int)(idx / KP), k = (int)(idx % KP);
    float v = (r < N && k < NUM_FEA) ? X[(long)r * NUM_FEA + k] : 0.f;
    Xbf[idx] = f2bf(v);
}

__global__ void convW_kernel(const float* __restrict__ W, ushort_t* __restrict__ Wt,
                             int NC, int KD, int KPAD) {
    int idx = blockIdx.x * blockDim.x + threadIdx.x;
    if (idx >= NC * KPAD) return;
    int n = idx / KPAD, k = idx % KPAD;
    Wt[idx] = (k < KD) ? f2bf(W[(long)k * NC + n]) : (ushort_t)0;
}

// ---------------- GEMM1 via MFMA bf16 ----------------

__global__ __launch_bounds__(256) void gemm1_mfma(const ushort_t* __restrict__ Xbf,
                                                  const ushort_t* __restrict__ Wt,
                                                  ushort_t* __restrict__ Hout, int N) {
    __shared__ ushort_t As[MROWS * LDK];
    __shared__ ushort_t Bs[F1 * LDK];
    int tid = threadIdx.x;
    int wave = tid >> 6, lane = tid & 63;
    int q = lane >> 4, l16 = lane & 15;
    int wm = (wave >> 1) * 64;
    int wn = (wave & 1) * 96;
    long row0 = (long)blockIdx.x * MROWS;

    floatx4 acc[4][6] = {};

    for (int k0 = 0; k0 < KP; k0 += 32) {
#pragma unroll
        for (int p = 0; p < 2; p++) {
            int idx = p * 256 + tid;
            int r = idx >> 2, ks = (idx & 3) * 8;
            *(int4*)&As[r * LDK + ks] = *(const int4*)&Xbf[(row0 + r) * KP + k0 + ks];
        }
#pragma unroll
        for (int p = 0; p < 3; p++) {
            int idx = p * 256 + tid;
            int r = idx >> 2, ks = (idx & 3) * 8;
            *(int4*)&Bs[r * LDK + ks] = *(const int4*)&Wt[(long)r * KP + k0 + ks];
        }
        __syncthreads();
        bf16x8 af[4], bfr[6];
#pragma unroll
        for (int rt = 0; rt < 4; rt++)
            af[rt] = *(const bf16x8*)&As[(wm + rt * 16 + l16) * LDK + q * 8];
#pragma unroll
        for (int ct = 0; ct < 6; ct++)
            bfr[ct] = *(const bf16x8*)&Bs[(wn + ct * 16 + l16) * LDK + q * 8];
#pragma unroll
        for (int rt = 0; rt < 4; rt++)
#pragma unroll
            for (int ct = 0; ct < 6; ct++)
                acc[rt][ct] = __builtin_amdgcn_mfma_f32_16x16x32_bf16(af[rt], bfr[ct], acc[rt][ct], 0, 0, 0);
        __syncthreads();
    }
#pragma unroll
    for (int rt = 0; rt < 4; rt++) {
#pragma unroll
        for (int r = 0; r < 4; r++) {
            long grow = row0 + wm + rt * 16 + q * 4 + r;
            if (grow < N) {
#pragma unroll
                for (int ct = 0; ct < 6; ct++)
                    Hout[grow * F1 + wn + ct * 16 + l16] = f2bf(acc[rt][ct][r]);
            }
        }
    }
}

// ---------------- GEMM2 via MFMA bf16 ----------------

__global__ __launch_bounds__(256) void gemm2_mfma(const ushort_t* __restrict__ Xbf,
                                                  const ushort_t* __restrict__ Wt,
                                                  ushort_t* __restrict__ Hout, int N) {
    __shared__ ushort_t As[MROWS * LDK];
    __shared__ ushort_t Bs[F2 * LDK];
    int tid = threadIdx.x;
    int wave = tid >> 6, lane = tid & 63;
    int q = lane >> 4, l16 = lane & 15;
    int wm = (wave >> 1) * 64;
    int wn = (wave & 1) * 32;
    long row0 = (long)blockIdx.x * MROWS;

    floatx4 acc[4][2] = {};

    for (int k0 = 0; k0 < KP2; k0 += 32) {
#pragma unroll
        for (int p = 0; p < 2; p++) {
            int idx = p * 256 + tid;
            int r = idx >> 2, ks = (idx & 3) * 8;
            *(int4*)&As[r * LDK + ks] = *(const int4*)&Xbf[(row0 + r) * KP2 + k0 + ks];
        }
        {
            int r = tid >> 2, ks = (tid & 3) * 8;
            if (r < F2)
                *(int4*)&Bs[r * LDK + ks] = *(const int4*)&Wt[(long)r * KP2 + k0 + ks];
        }
        __syncthreads();
        bf16x8 af[4], bfr[2];
#pragma unroll
        for (int rt = 0; rt < 4; rt++)
            af[rt] = *(const bf16x8*)&As[(wm + rt * 16 + l16) * LDK + q * 8];
#pragma unroll
        for (int ct = 0; ct < 2; ct++)
            bfr[ct] = *(const bf16x8*)&Bs[(wn + ct * 16 + l16) * LDK + q * 8];
#pragma unroll
        for (int rt = 0; rt < 4; rt++)
#pragma unroll
            for (int ct = 0; ct < 2; ct++)
                acc[rt][ct] = __builtin_amdgcn_mfma_f32_16x16x32_bf16(af[rt], bfr[ct], acc[rt][ct], 0, 0, 0);
        __syncthreads();
    }
#pragma unroll
    for (int rt = 0; rt < 4; rt++) {
#pragma unroll
        for (int r = 0; r < 4; r++) {
            long grow = row0 + wm + rt * 16 + q * 4 + r;
            if (grow < N) {
#pragma unroll
                for (int ct = 0; ct < 2; ct++)
                    Hout[grow * F2 + wn + ct * 16 + l16] = f2bf(acc[rt][ct][r]);
            }
        }
    }
}

// ---------------- attention coefficients (bf16 h) ----------------

template<int H, int C>
__global__ void att_bf_kernel(const ushort_t* __restrict__ h, const float* __restrict__ att_s,
                              const float* __restrict__ att_d, float* __restrict__ as_,
                              float* __restrict__ ad_, int N) {
    int idx = blockIdx.x * blockDim.x + threadIdx.x;
    if (idx >= N * H) return;
    int n = idx / H, hd = idx % H;
    const ushort_t* hp = h + (long)n * H * C + hd * C;
    const float* sp = att_s + hd * C;
    const float* dp = att_d + hd * C;
    float ss = 0.f, dd = 0.f;
#pragma unroll
    for (int c = 0; c < C; c++) {
        float v = bf2f(hp[c]);
        ss += v * sp[c];
        dd += v * dp[c];
    }
    as_[idx] = ss;
    ad_[idx] = dd;
}

// ---------------- edge weights: ew[p*H+hd] = exp(lrelu(as[src]+ad[dst])) ----------------

template<int H>
__global__ __launch_bounds__(256) void ew_kernel(const int* __restrict__ esrc,
                                                 const int* __restrict__ edst,
                                                 const float* __restrict__ as_,
                                                 const float* __restrict__ ad_,
                                                 float* __restrict__ ew, long total) {
    long idx = (long)blockIdx.x * 256 + threadIdx.x;
    if (idx >= total) return;
    int p = (int)(idx / H), hd = (int)(idx % H);
    int s = esrc[p], d = edst[p];
    ew[idx] = __expf(lrelu(as_[s * H + hd] + ad_[d * H + hd]));
}

// ---------------- gather layer 1: pure weighted gather, 8-way predicated ----------------

__global__ __launch_bounds__(192) void gather1_kernel(const int* __restrict__ rowstart,
                                                      const int* __restrict__ esrc,
                                                      const float* __restrict__ ew,
                                                      const ushort_t* __restrict__ h,
                                                      const float* __restrict__ bias,
                                                      ushort_t* __restrict__ xout, int N) {
    int d = blockIdx.x;
    if (d >= N) return;
    int t = threadIdx.x;
    int hd = t >> 4;
    int beg = rowstart[d], end = rowstart[d + 1];
    const ushort_t* hp = h + t;
    float accn = 0.f, accd = 0.f;
    for (int p = beg; p < end; p += 8) {
        int   s[8];
        float w[8], g[8];
#pragma unroll
        for (int i = 0; i < 8; i++) {
            int pp = p + i;
            bool valid = pp < end;
            int pc = valid ? pp : beg;
            s[i] = esrc[pc];
            w[i] = valid ? ew[pc * NHEAD1 + hd] : 0.f;
        }
#pragma unroll
        for (int i = 0; i < 8; i++)
            g[i] = bf2f(hp[(long)s[i] * F1]);
#pragma unroll
        for (int i = 0; i < 8; i++) {
            accn += w[i] * g[i];
            accd += w[i];
        }
    }
    float v = accn / accd + bias[t];
    v = v > 0.f ? v : (__expf(v) - 1.f);
    xout[(long)d * F1 + t] = f2bf(v);
}

// ---------------- gather layer 2: 4 nodes/block, 8-way predicated ----------------

__global__ __launch_bounds__(256) void gather2_kernel(const int* __restrict__ rowstart,
                                                      const int* __restrict__ esrc,
                                                      const float* __restrict__ ew,
                                                      const ushort_t* __restrict__ h,
                                                      const float* __restrict__ bias,
                                                      float* __restrict__ xout, int N) {
    int d = blockIdx.x * 4 + (threadIdx.x >> 6);
    if (d >= N) return;
    int t = threadIdx.x & 63;
    int hd = t >> 3;
    int beg = rowstart[d], end = rowstart[d + 1];
    const ushort_t* hp = h + t;
    float accn = 0.f, accd = 0.f;
    for (int p = beg; p < end; p += 8) {
        int   s[8];
        float w[8], g[8];
#pragma unroll
        for (int i = 0; i < 8; i++) {
            int pp = p + i;
            bool valid = pp < end;
            int pc = valid ? pp : beg;
            s[i] = esrc[pc];
            w[i] = valid ? ew[pc * NHEAD2 + hd] : 0.f;
        }
#pragma unroll
        for (int i = 0; i < 8; i++)
            g[i] = bf2f(hp[(long)s[i] * F2]);
#pragma unroll
        for (int i = 0; i < 8; i++) {
            accn += w[i] * g[i];
            accd += w[i];
        }
    }
    float v = accn / accd + bias[t];
    xout[(long)d * F2 + t] = v > 0.f ? v : (__expf(v) - 1.f);
}

// ---------------- pair predictor ----------------

__global__ void pair_kernel(const float* __restrict__ x, const int* __restrict__ n1,
                            const int* __restrict__ n2, const float* __restrict__ linW,
                            const float* __restrict__ linb, float* __restrict__ y, int P) {
    int idx = blockIdx.x * blockDim.x + threadIdx.x;
    if (idx >= P) return;
    const float4* xa = (const float4*)(x + (long)n1[idx] * F2);
    const float4* xb = (const float4*)(x + (long)n2[idx] * F2);
    float a0 = linb[0], a1 = linb[1];
#pragma unroll
    for (int k4 = 0; k4 < F2 / 4; k4++) {
        float4 v = xa[k4];
        int k = k4 * 4;
        a0 += v.x * linW[2 * k] + v.y * linW[2 * (k + 1)] + v.z * linW[2 * (k + 2)] + v.w * linW[2 * (k + 3)];
        a1 += v.x * linW[2 * k + 1] + v.y * linW[2 * (k + 1) + 1] + v.z * linW[2 * (k + 2) + 1] + v.w * linW[2 * (k + 3) + 1];
    }
#pragma unroll
    for (int k4 = 0; k4 < F2 / 4; k4++) {
        float4 v = xb[k4];
        int k = F2 + k4 * 4;
        a0 += v.x * linW[2 * k] + v.y * linW[2 * (k + 1)] + v.z * linW[2 * (k + 2)] + v.w * linW[2 * (k + 3)];
        a1 += v.x * linW[2 * k + 1] + v.y * linW[2 * (k + 1) + 1] + v.z * linW[2 * (k + 2) + 1] + v.w * linW[2 * (k + 3) + 1];
    }
    y[2 * idx]     = 1.f / (1.f + __expf(-a0));
    y[2 * idx + 1] = 1.f / (1.f + __expf(-a1));
}

// ---------------- launch ----------------

extern "C" void kernel_launch(void* const* d_in, const int* in_sizes, int n_in,
                              void* d_out, int out_size, void* d_ws, size_t ws_size,
                              hipStream_t stream) {
    const float* features = (const float*)d_in[0];
    const int*   ei       = (const int*)d_in[1];
    const int*   n1       = (const int*)d_in[2];
    const int*   n2       = (const int*)d_in[3];
    const float* W1       = (const float*)d_in[4];
    const float* att_s1   = (const float*)d_in[5];
    const float* att_d1   = (const float*)d_in[6];
    const float* b1       = (const float*)d_in[7];
    const float* W2       = (const float*)d_in[8];
    const float* att_s2   = (const float*)d_in[9];
    const float* att_d2   = (const float*)d_in[10];
    const float* b2       = (const float*)d_in[11];
    const float* linW     = (const float*)d_in[12];
    const float* linb     = (const float*)d_in[13];

    const int N = in_sizes[0] / NUM_FEA;      // 50000
    const int E = in_sizes[1] / 2;            // 800000
    const int P = in_sizes[2];                // 16384
    const int Etot = E + N;                   // 850000

    const int nblk = (N + MROWS - 1) / MROWS;    // 391
    const int NPAD = nblk * MROWS;               // 50048
    const int nsb = (N + 255) / 256;             // scan blocks (196)

    // compact workspace layout (float elements)
    float* ws = (float*)d_ws;
    long o = 0;
    float* ew   = ws + o; o += (long)Etot * NHEAD1;          // 10.2M; reused for ew2
    float* h1r  = ws + o; o += (long)N * F1 / 2;             // h1b bf16
    float* xr   = ws + o; o += ((long)NPAD * KP + 1) / 2;    // Xbf then x1bf
    float* as1  = ws + o; o += (long)N * NHEAD1;
    float* ad1  = ws + o; o += (long)N * NHEAD1;
    float* h2r  = ws + o; o += (long)N * F2 / 2;             // h2b bf16
    float* as2  = ws + o; o += (long)N * NHEAD2;
    float* ad2  = ws + o; o += (long)N * NHEAD2;
    float* w1r  = ws + o; o += (F1 * KP + 1) / 2;            // Wt1 bf16
    float* w2r  = ws + o; o += (F2 * KP2 + 1) / 2;           // Wt2 bf16
    int* rowstart = (int*)(ws + o); o += N + 1;
    int* esrc = (int*)(ws + o); o += Etot;
    int* edst = (int*)(ws + o); o += Etot;
    int* cnt  = (int*)(ws + o); o += N;
    int* cnt2 = (int*)(ws + o); o += N;
    int* part = (int*)(ws + o); o += N;
    int* bsum = (int*)(ws + o); o += 256;

    ushort_t* h1b  = (ushort_t*)h1r;
    ushort_t* Xbf  = (ushort_t*)xr;
    ushort_t* x1bf = (ushort_t*)xr;    // after Xbf dead
    ushort_t* h2b  = (ushort_t*)h2r;
    ushort_t* Wt1  = (ushort_t*)w1r;
    ushort_t* Wt2  = (ushort_t*)w2r;

    float* y_out = (float*)d_out;
    float* x_out = (float*)d_out + (long)2 * P;

    hipMemsetAsync(cnt, 0, (size_t)2 * N * sizeof(int), stream);

    // CSR build
    deg_kernel<<<(Etot + 255) / 256, 256, 0, stream>>>(ei, cnt, E, Etot);
    scan1_kernel<<<nsb, 256, 0, stream>>>(cnt, part, bsum, N);
    scan2_kernel<<<1, 256, 0, stream>>>(bsum, nsb);
    scan3_kernel<<<nsb, 256, 0, stream>>>(part, bsum, rowstart, N, Etot);
    fill_kernel<<<(Etot + 255) / 256, 256, 0, stream>>>(ei, rowstart, cnt2, esrc, edst, E, Etot);

    // layer 1
    long totX = (long)NPAD * KP;
    convX_kernel<<<(int)((totX + 255) / 256), 256, 0, stream>>>(features, Xbf, N, totX);
    convW_kernel<<<(F1 * KP + 255) / 256, 256, 0, stream>>>(W1, Wt1, F1, NUM_FEA, KP);
    gemm1_mfma<<<nblk, 256, 0, stream>>>(Xbf, Wt1, h1b, N);
    att_bf_kernel<NHEAD1, HID1><<<(N * NHEAD1 + 255) / 256, 256, 0, stream>>>(h1b, att_s1, att_d1, as1, ad1, N);
    long tot1 = (long)Etot * NHEAD1;
    ew_kernel<NHEAD1><<<(int)((tot1 + 255) / 256), 256, 0, stream>>>(esrc, edst, as1, ad1, ew, tot1);
    gather1_kernel<<<N, 192, 0, stream>>>(rowstart, esrc, ew, h1b, b1, x1bf, N);

    // layer 2
    convW_kernel<<<(F2 * KP2 + 255) / 256, 256, 0, stream>>>(W2, Wt2, F2, F1, KP2);
    gemm2_mfma<<<nblk, 256, 0, stream>>>(x1bf, Wt2, h2b, N);
    att_bf_kernel<NHEAD2, HID2><<<(N * NHEAD2 + 255) / 256, 256, 0, stream>>>(h2b, att_s2, att_d2, as2, ad2, N);
    long tot2 = (long)Etot * NHEAD2;
    ew_kernel<NHEAD2><<<(int)((tot2 + 255) / 256), 256, 0, stream>>>(esrc, edst, as2, ad2, ew, tot2);
    gather2_kernel<<<(N + 3) / 4, 256, 0, stream>>>(rowstart, esrc, ew, h2b, b2, x_out, N);

    // pair predictor
    pair_kernel<<<(P + 255) / 256, 256, 0, stream>>>(x_out, n1, n2, linW, linb, y_out, P);
}

// Round 6
// 382.457 us; speedup vs baseline: 1.0858x; 1.0858x over previous
//
#include <hip/hip_runtime.h>
#include <hip/hip_bf16.h>

#define HID1 16
#define NHEAD1 12
#define F1 (HID1*NHEAD1)   // 192
#define HID2 8
#define NHEAD2 8
#define F2 (HID2*NHEAD2)   // 64
#define NUM_FEA 213
#define NEG_SLOPE 0.2f
#define KP 224             // layer-1 K padded to 7*32 for MFMA
#define KP2 192            // layer-2 K (already 6*32)
#define LDK 40             // LDS k-stride (bf16 elems): 80B -> bank stride 20, 2-way max (free)
#define MROWS 128          // gemm block row tile

typedef __attribute__((ext_vector_type(8))) __bf16 bf16x8;
typedef __attribute__((ext_vector_type(4))) float floatx4;
typedef unsigned short ushort_t;

static __device__ __forceinline__ unsigned short f2bf(float f) {
    unsigned u = __float_as_uint(f);
    unsigned r = (u + 0x7fffu + ((u >> 16) & 1u)) >> 16;   // RNE
    return (unsigned short)r;
}
static __device__ __forceinline__ float bf2f(unsigned short u) {
    return __uint_as_float(((unsigned)u) << 16);
}
static __device__ __forceinline__ float lrelu(float e) {
    return e > 0.f ? e : NEG_SLOPE * e;
}

// ---------------- CSR build ----------------

__global__ void deg_kernel(const int* __restrict__ ei, int* __restrict__ cnt, int E, int Etot) {
    int e = blockIdx.x * blockDim.x + threadIdx.x;
    if (e >= Etot) return;
    int d = (e < E) ? ei[E + e] : (e - E);
    atomicAdd(&cnt[d], 1);
}

__global__ __launch_bounds__(256) void scan1_kernel(const int* __restrict__ cnt,
                                                    int* __restrict__ part,
                                                    int* __restrict__ bsum, int N) {
    __shared__ int tmp[256];
    int tid = threadIdx.x;
    int i = blockIdx.x * 256 + tid;
    int v = (i < N) ? cnt[i] : 0;
    tmp[tid] = v;
    __syncthreads();
    for (int off = 1; off < 256; off <<= 1) {
        int add = (tid >= off) ? tmp[tid - off] : 0;
        __syncthreads();
        tmp[tid] += add;
        __syncthreads();
    }
    if (i < N) part[i] = tmp[tid] - v;
    if (tid == 255) bsum[blockIdx.x] = tmp[255];
}

__global__ __launch_bounds__(256) void scan2_kernel(int* __restrict__ bsum, int nb) {
    __shared__ int tmp[256];
    int tid = threadIdx.x;
    int v = (tid < nb) ? bsum[tid] : 0;
    tmp[tid] = v;
    __syncthreads();
    for (int off = 1; off < 256; off <<= 1) {
        int add = (tid >= off) ? tmp[tid - off] : 0;
        __syncthreads();
        tmp[tid] += add;
        __syncthreads();
    }
    if (tid < nb) bsum[tid] = tmp[tid] - v;
}

__global__ __launch_bounds__(256) void scan3_kernel(const int* __restrict__ part,
                                                    const int* __restrict__ bsum,
                                                    int* __restrict__ rowstart, int N, int Etot) {
    int i = blockIdx.x * 256 + threadIdx.x;
    if (i < N) rowstart[i] = part[i] + bsum[blockIdx.x];
    if (i == 0) rowstart[N] = Etot;
}

__global__ void fill_kernel(const int* __restrict__ ei, const int* __restrict__ rowstart,
                            int* __restrict__ cnt2, int* __restrict__ esrc, int E, int Etot) {
    int e = blockIdx.x * blockDim.x + threadIdx.x;
    if (e >= Etot) return;
    int s, d;
    if (e < E) { s = ei[e]; d = ei[E + e]; } else { s = e - E; d = s; }
    esrc[rowstart[d] + atomicAdd(&cnt2[d], 1)] = s;
}

// ---------------- bf16 conversion ----------------

__global__ void convX_kernel(const float* __restrict__ X, ushort_t* __restrict__ Xbf,
                             int N, long total) {
    long idx = (long)blockIdx.x * blockDim.x + threadIdx.x;
    if (idx >= total) return;
    int r = (int)(idx / KP), k = (int)(idx % KP);
    float v = (r < N && k < NUM_FEA) ? X[(long)r * NUM_FEA + k] : 0.f;
    Xbf[idx] = f2bf(v);
}

// both weight transposes in one launch
__global__ void convW_both_kernel(const float* __restrict__ W1, ushort_t* __restrict__ Wt1,
                                  const float* __restrict__ W2, ushort_t* __restrict__ Wt2) {
    int idx = blockIdx.x * blockDim.x + threadIdx.x;
    if (idx < F1 * KP) {
        int n = idx / KP, k = idx % KP;
        Wt1[idx] = (k < NUM_FEA) ? f2bf(W1[(long)k * F1 + n]) : (ushort_t)0;
    } else {
        int j = idx - F1 * KP;
        if (j < F2 * KP2) {
            int n = j / KP2, k = j % KP2;
            Wt2[j] = f2bf(W2[(long)k * F2 + n]);
        }
    }
}

// ---------------- GEMM1 via MFMA bf16 ----------------

__global__ __launch_bounds__(256) void gemm1_mfma(const ushort_t* __restrict__ Xbf,
                                                  const ushort_t* __restrict__ Wt,
                                                  ushort_t* __restrict__ Hout, int N) {
    __shared__ ushort_t As[MROWS * LDK];
    __shared__ ushort_t Bs[F1 * LDK];
    int tid = threadIdx.x;
    int wave = tid >> 6, lane = tid & 63;
    int q = lane >> 4, l16 = lane & 15;
    int wm = (wave >> 1) * 64;
    int wn = (wave & 1) * 96;
    long row0 = (long)blockIdx.x * MROWS;

    floatx4 acc[4][6] = {};

    for (int k0 = 0; k0 < KP; k0 += 32) {
#pragma unroll
        for (int p = 0; p < 2; p++) {
            int idx = p * 256 + tid;
            int r = idx >> 2, ks = (idx & 3) * 8;
            *(int4*)&As[r * LDK + ks] = *(const int4*)&Xbf[(row0 + r) * KP + k0 + ks];
        }
#pragma unroll
        for (int p = 0; p < 3; p++) {
            int idx = p * 256 + tid;
            int r = idx >> 2, ks = (idx & 3) * 8;
            *(int4*)&Bs[r * LDK + ks] = *(const int4*)&Wt[(long)r * KP + k0 + ks];
        }
        __syncthreads();
        bf16x8 af[4], bfr[6];
#pragma unroll
        for (int rt = 0; rt < 4; rt++)
            af[rt] = *(const bf16x8*)&As[(wm + rt * 16 + l16) * LDK + q * 8];
#pragma unroll
        for (int ct = 0; ct < 6; ct++)
            bfr[ct] = *(const bf16x8*)&Bs[(wn + ct * 16 + l16) * LDK + q * 8];
#pragma unroll
        for (int rt = 0; rt < 4; rt++)
#pragma unroll
            for (int ct = 0; ct < 6; ct++)
                acc[rt][ct] = __builtin_amdgcn_mfma_f32_16x16x32_bf16(af[rt], bfr[ct], acc[rt][ct], 0, 0, 0);
        __syncthreads();
    }
#pragma unroll
    for (int rt = 0; rt < 4; rt++) {
#pragma unroll
        for (int r = 0; r < 4; r++) {
            long grow = row0 + wm + rt * 16 + q * 4 + r;
            if (grow < N) {
#pragma unroll
                for (int ct = 0; ct < 6; ct++)
                    Hout[grow * F1 + wn + ct * 16 + l16] = f2bf(acc[rt][ct][r]);
            }
        }
    }
}

// ---------------- GEMM2 via MFMA bf16 ----------------

__global__ __launch_bounds__(256) void gemm2_mfma(const ushort_t* __restrict__ Xbf,
                                                  const ushort_t* __restrict__ Wt,
                                                  ushort_t* __restrict__ Hout, int N) {
    __shared__ ushort_t As[MROWS * LDK];
    __shared__ ushort_t Bs[F2 * LDK];
    int tid = threadIdx.x;
    int wave = tid >> 6, lane = tid & 63;
    int q = lane >> 4, l16 = lane & 15;
    int wm = (wave >> 1) * 64;
    int wn = (wave & 1) * 32;
    long row0 = (long)blockIdx.x * MROWS;

    floatx4 acc[4][2] = {};

    for (int k0 = 0; k0 < KP2; k0 += 32) {
#pragma unroll
        for (int p = 0; p < 2; p++) {
            int idx = p * 256 + tid;
            int r = idx >> 2, ks = (idx & 3) * 8;
            *(int4*)&As[r * LDK + ks] = *(const int4*)&Xbf[(row0 + r) * KP2 + k0 + ks];
        }
        {
            int r = tid >> 2, ks = (tid & 3) * 8;
            if (r < F2)
                *(int4*)&Bs[r * LDK + ks] = *(const int4*)&Wt[(long)r * KP2 + k0 + ks];
        }
        __syncthreads();
        bf16x8 af[4], bfr[2];
#pragma unroll
        for (int rt = 0; rt < 4; rt++)
            af[rt] = *(const bf16x8*)&As[(wm + rt * 16 + l16) * LDK + q * 8];
#pragma unroll
        for (int ct = 0; ct < 2; ct++)
            bfr[ct] = *(const bf16x8*)&Bs[(wn + ct * 16 + l16) * LDK + q * 8];
#pragma unroll
        for (int rt = 0; rt < 4; rt++)
#pragma unroll
            for (int ct = 0; ct < 2; ct++)
                acc[rt][ct] = __builtin_amdgcn_mfma_f32_16x16x32_bf16(af[rt], bfr[ct], acc[rt][ct], 0, 0, 0);
        __syncthreads();
    }
#pragma unroll
    for (int rt = 0; rt < 4; rt++) {
#pragma unroll
        for (int r = 0; r < 4; r++) {
            long grow = row0 + wm + rt * 16 + q * 4 + r;
            if (grow < N) {
#pragma unroll
                for (int ct = 0; ct < 2; ct++)
                    Hout[grow * F2 + wn + ct * 16 + l16] = f2bf(acc[rt][ct][r]);
            }
        }
    }
}

// ---------------- attention coefficients (bf16 h) ----------------

template<int H, int C>
__global__ void att_bf_kernel(const ushort_t* __restrict__ h, const float* __restrict__ att_s,
                              const float* __restrict__ att_d, float* __restrict__ as_,
                              float* __restrict__ ad_, int N) {
    int idx = blockIdx.x * blockDim.x + threadIdx.x;
    if (idx >= N * H) return;
    int n = idx / H, hd = idx % H;
    const ushort_t* hp = h + (long)n * H * C + hd * C;
    const float* sp = att_s + hd * C;
    const float* dp = att_d + hd * C;
    float ss = 0.f, dd = 0.f;
#pragma unroll
    for (int c = 0; c < C; c++) {
        float v = bf2f(hp[c]);
        ss += v * sp[c];
        dd += v * dp[c];
    }
    as_[idx] = ss;
    ad_[idx] = dd;
}

// ---------------- gather layer 1: shuffle-deduped exp, 8-way MLP ----------------
// wave covers 64 cols = 4 heads; lane j(&31): computes exp for edge j>>2, head j&3

__global__ __launch_bounds__(192) void gather1_kernel(const int* __restrict__ rowstart,
                                                      const int* __restrict__ esrc,
                                                      const float* __restrict__ as_,
                                                      const float* __restrict__ ad_,
                                                      const ushort_t* __restrict__ h,
                                                      const float* __restrict__ bias,
                                                      ushort_t* __restrict__ xout, int N) {
    int d = blockIdx.x;
    if (d >= N) return;
    int t = threadIdx.x;
    int lane = t & 63;
    int base = (t >> 6) * 4;      // head base of this wave
    int hdl = (t >> 4) & 3;       // own head within wave
    int j = lane & 31;
    int ie = j >> 2, hq = j & 3;  // this lane's (edge-in-chunk, head) for exp duty
    int beg = rowstart[d], end = rowstart[d + 1];
    float advq = ad_[d * NHEAD1 + base + hq];
    const ushort_t* hp = h + t;
    float accn = 0.f, accd = 0.f;
    for (int p = beg; p < end; p += 8) {
        int s[8];
        float g[8];
#pragma unroll
        for (int i = 0; i < 8; i++) {
            int pp = p + i;
            s[i] = esrc[pp < end ? pp : beg];
        }
#pragma unroll
        for (int i = 0; i < 8; i++)
            g[i] = bf2f(hp[(long)s[i] * F1]);
        // one exp per lane for (edge ie, head base+hq)
        int pe = p + ie;
        int sq = esrc[pe < end ? pe : beg];
        float aval = as_[sq * NHEAD1 + base + hq];
        float w = (pe < end) ? __expf(lrelu(aval + advq)) : 0.f;
#pragma unroll
        for (int i = 0; i < 8; i++) {
            float wi = __shfl(w, (i << 2) | hdl, 64);
            accn += wi * g[i];
            accd += wi;
        }
    }
    float v = accn / accd + bias[t];
    v = v > 0.f ? v : (__expf(v) - 1.f);
    xout[(long)d * F1 + t] = f2bf(v);
}

// ---------------- gather layer 2: one wave/node, shuffle-deduped exp ----------------
// wave covers 64 cols = 8 heads; lane: computes exp for edge lane>>3, head lane&7

__global__ __launch_bounds__(256) void gather2_kernel(const int* __restrict__ rowstart,
                                                      const int* __restrict__ esrc,
                                                      const float* __restrict__ as_,
                                                      const float* __restrict__ ad_,
                                                      const ushort_t* __restrict__ h,
                                                      const float* __restrict__ bias,
                                                      float* __restrict__ xout, int N) {
    int d = blockIdx.x * 4 + (threadIdx.x >> 6);
    if (d >= N) return;
    int lane = threadIdx.x & 63;
    int hd = lane >> 3;           // own head
    int ie = lane >> 3, hq = lane & 7;   // exp duty: edge ie, head hq
    int beg = rowstart[d], end = rowstart[d + 1];
    float advq = ad_[d * NHEAD2 + hq];
    const ushort_t* hp = h + lane;
    float accn = 0.f, accd = 0.f;
    for (int p = beg; p < end; p += 8) {
        int s[8];
        float g[8];
#pragma unroll
        for (int i = 0; i < 8; i++) {
            int pp = p + i;
            s[i] = esrc[pp < end ? pp : beg];
        }
#pragma unroll
        for (int i = 0; i < 8; i++)
            g[i] = bf2f(hp[(long)s[i] * F2]);
        int pe = p + ie;
        int sq = esrc[pe < end ? pe : beg];
        float aval = as_[sq * NHEAD2 + hq];
        float w = (pe < end) ? __expf(lrelu(aval + advq)) : 0.f;
#pragma unroll
        for (int i = 0; i < 8; i++) {
            float wi = __shfl(w, (i << 3) | hd, 64);
            accn += wi * g[i];
            accd += wi;
        }
    }
    float v = accn / accd + bias[lane];
    xout[(long)d * F2 + lane] = v > 0.f ? v : (__expf(v) - 1.f);
}

// ---------------- pair predictor ----------------

__global__ void pair_kernel(const float* __restrict__ x, const int* __restrict__ n1,
                            const int* __restrict__ n2, const float* __restrict__ linW,
                            const float* __restrict__ linb, float* __restrict__ y, int P) {
    int idx = blockIdx.x * blockDim.x + threadIdx.x;
    if (idx >= P) return;
    const float4* xa = (const float4*)(x + (long)n1[idx] * F2);
    const float4* xb = (const float4*)(x + (long)n2[idx] * F2);
    float a0 = linb[0], a1 = linb[1];
#pragma unroll
    for (int k4 = 0; k4 < F2 / 4; k4++) {
        float4 v = xa[k4];
        int k = k4 * 4;
        a0 += v.x * linW[2 * k] + v.y * linW[2 * (k + 1)] + v.z * linW[2 * (k + 2)] + v.w * linW[2 * (k + 3)];
        a1 += v.x * linW[2 * k + 1] + v.y * linW[2 * (k + 1) + 1] + v.z * linW[2 * (k + 2) + 1] + v.w * linW[2 * (k + 3) + 1];
    }
#pragma unroll
    for (int k4 = 0; k4 < F2 / 4; k4++) {
        float4 v = xb[k4];
        int k = F2 + k4 * 4;
        a0 += v.x * linW[2 * k] + v.y * linW[2 * (k + 1)] + v.z * linW[2 * (k + 2)] + v.w * linW[2 * (k + 3)];
        a1 += v.x * linW[2 * k + 1] + v.y * linW[2 * (k + 1) + 1] + v.z * linW[2 * (k + 2) + 1] + v.w * linW[2 * (k + 3) + 1];
    }
    y[2 * idx]     = 1.f / (1.f + __expf(-a0));
    y[2 * idx + 1] = 1.f / (1.f + __expf(-a1));
}

// ---------------- launch ----------------

extern "C" void kernel_launch(void* const* d_in, const int* in_sizes, int n_in,
                              void* d_out, int out_size, void* d_ws, size_t ws_size,
                              hipStream_t stream) {
    const float* features = (const float*)d_in[0];
    const int*   ei       = (const int*)d_in[1];
    const int*   n1       = (const int*)d_in[2];
    const int*   n2       = (const int*)d_in[3];
    const float* W1       = (const float*)d_in[4];
    const float* att_s1   = (const float*)d_in[5];
    const float* att_d1   = (const float*)d_in[6];
    const float* b1       = (const float*)d_in[7];
    const float* W2       = (const float*)d_in[8];
    const float* att_s2   = (const float*)d_in[9];
    const float* att_d2   = (const float*)d_in[10];
    const float* b2       = (const float*)d_in[11];
    const float* linW     = (const float*)d_in[12];
    const float* linb     = (const float*)d_in[13];

    const int N = in_sizes[0] / NUM_FEA;      // 50000
    const int E = in_sizes[1] / 2;            // 800000
    const int P = in_sizes[2];                // 16384
    const int Etot = E + N;                   // 850000

    const int nblk = (N + MROWS - 1) / MROWS;    // 391
    const int NPAD = nblk * MROWS;               // 50048
    const int nsb = (N + 255) / 256;             // scan blocks (196)

    float* ws = (float*)d_ws;
    long o = 0;
    float* h1r  = ws + o; o += (long)N * F1 / 2;             // h1b bf16
    float* xr   = ws + o; o += ((long)NPAD * KP + 1) / 2;    // Xbf then x1bf
    float* as1  = ws + o; o += (long)N * NHEAD1;
    float* ad1  = ws + o; o += (long)N * NHEAD1;
    float* h2r  = ws + o; o += (long)N * F2 / 2;             // h2b bf16
    float* as2  = ws + o; o += (long)N * NHEAD2;
    float* ad2  = ws + o; o += (long)N * NHEAD2;
    float* w1r  = ws + o; o += (F1 * KP + 1) / 2;            // Wt1 bf16
    float* w2r  = ws + o; o += (F2 * KP2 + 1) / 2;           // Wt2 bf16
    int* rowstart = (int*)(ws + o); o += N + 1;
    int* esrc = (int*)(ws + o); o += Etot;
    int* cnt  = (int*)(ws + o); o += N;
    int* cnt2 = (int*)(ws + o); o += N;
    int* part = (int*)(ws + o); o += N;
    int* bsum = (int*)(ws + o); o += 256;

    ushort_t* h1b  = (ushort_t*)h1r;
    ushort_t* Xbf  = (ushort_t*)xr;
    ushort_t* x1bf = (ushort_t*)xr;    // after Xbf dead
    ushort_t* h2b  = (ushort_t*)h2r;
    ushort_t* Wt1  = (ushort_t*)w1r;
    ushort_t* Wt2  = (ushort_t*)w2r;

    float* y_out = (float*)d_out;
    float* x_out = (float*)d_out + (long)2 * P;

    hipMemsetAsync(cnt, 0, (size_t)2 * N * sizeof(int), stream);

    // CSR build
    deg_kernel<<<(Etot + 255) / 256, 256, 0, stream>>>(ei, cnt, E, Etot);
    scan1_kernel<<<nsb, 256, 0, stream>>>(cnt, part, bsum, N);
    scan2_kernel<<<1, 256, 0, stream>>>(bsum, nsb);
    scan3_kernel<<<nsb, 256, 0, stream>>>(part, bsum, rowstart, N, Etot);
    fill_kernel<<<(Etot + 255) / 256, 256, 0, stream>>>(ei, rowstart, cnt2, esrc, E, Etot);

    // weight prep (independent of CSR)
    convW_both_kernel<<<(F1 * KP + F2 * KP2 + 255) / 256, 256, 0, stream>>>(W1, Wt1, W2, Wt2);

    // layer 1
    long totX = (long)NPAD * KP;
    convX_kernel<<<(int)((totX + 255) / 256), 256, 0, stream>>>(features, Xbf, N, totX);
    gemm1_mfma<<<nblk, 256, 0, stream>>>(Xbf, Wt1, h1b, N);
    att_bf_kernel<NHEAD1, HID1><<<(N * NHEAD1 + 255) / 256, 256, 0, stream>>>(h1b, att_s1, att_d1, as1, ad1, N);
    gather1_kernel<<<N, 192, 0, stream>>>(rowstart, esrc, as1, ad1, h1b, b1, x1bf, N);

    // layer 2
    gemm2_mfma<<<nblk, 256, 0, stream>>>(x1bf, Wt2, h2b, N);
    att_bf_kernel<NHEAD2, HID2><<<(N * NHEAD2 + 255) / 256, 256, 0, stream>>>(h2b, att_s2, att_d2, as2, ad2, N);
    gather2_kernel<<<(N + 3) / 4, 256, 0, stream>>>(rowstart, esrc, as2, ad2, h2b, b2, x_out, N);

    // pair predictor
    pair_kernel<<<(P + 255) / 256, 256, 0, stream>>>(x_out, n1, n2, linW, linb, y_out, P);
}

// Round 7
// 344.897 us; speedup vs baseline: 1.2041x; 1.1089x over previous
//
#include <hip/hip_runtime.h>
#include <hip/hip_bf16.h>

#define HID1 16
#define NHEAD1 12
#define F1 (HID1*NHEAD1)   // 192
#define HID2 8
#define NHEAD2 8
#define F2 (HID2*NHEAD2)   // 64
#define NUM_FEA 213
#define NEG_SLOPE 0.2f
#define KP 224             // layer-1 K padded to 7*32 for MFMA
#define KP2 192            // layer-2 K (already 6*32)
#define LDK 40             // LDS k-stride (bf16 elems): 80B -> bank stride 20, 2-way max (free)
#define MROWS 128          // gemm block row tile

typedef __attribute__((ext_vector_type(8))) __bf16 bf16x8;
typedef __attribute__((ext_vector_type(4))) float floatx4;
typedef unsigned short ushort_t;

static __device__ __forceinline__ unsigned short f2bf(float f) {
    unsigned u = __float_as_uint(f);
    unsigned r = (u + 0x7fffu + ((u >> 16) & 1u)) >> 16;   // RNE
    return (unsigned short)r;
}
static __device__ __forceinline__ float bf2f(unsigned short u) {
    return __uint_as_float(((unsigned)u) << 16);
}
static __device__ __forceinline__ float lrelu(float e) {
    return e > 0.f ? e : NEG_SLOPE * e;
}
static __device__ __forceinline__ float elu(float v) {
    return v > 0.f ? v : (__expf(v) - 1.f);
}

// ---------------- CSR build ----------------

__global__ void deg_kernel(const int* __restrict__ ei, int* __restrict__ cnt, int E, int Etot) {
    int e = blockIdx.x * blockDim.x + threadIdx.x;
    if (e >= Etot) return;
    int d = (e < E) ? ei[E + e] : (e - E);
    atomicAdd(&cnt[d], 1);
}

__global__ __launch_bounds__(256) void scan1_kernel(const int* __restrict__ cnt,
                                                    int* __restrict__ part,
                                                    int* __restrict__ bsum, int N) {
    __shared__ int tmp[256];
    int tid = threadIdx.x;
    int i = blockIdx.x * 256 + tid;
    int v = (i < N) ? cnt[i] : 0;
    tmp[tid] = v;
    __syncthreads();
    for (int off = 1; off < 256; off <<= 1) {
        int add = (tid >= off) ? tmp[tid - off] : 0;
        __syncthreads();
        tmp[tid] += add;
        __syncthreads();
    }
    if (i < N) part[i] = tmp[tid] - v;
    if (tid == 255) bsum[blockIdx.x] = tmp[255];
}

__global__ __launch_bounds__(256) void scan2_kernel(int* __restrict__ bsum, int nb) {
    __shared__ int tmp[256];
    int tid = threadIdx.x;
    int v = (tid < nb) ? bsum[tid] : 0;
    tmp[tid] = v;
    __syncthreads();
    for (int off = 1; off < 256; off <<= 1) {
        int add = (tid >= off) ? tmp[tid - off] : 0;
        __syncthreads();
        tmp[tid] += add;
        __syncthreads();
    }
    if (tid < nb) bsum[tid] = tmp[tid] - v;
}

__global__ __launch_bounds__(256) void scan3_kernel(const int* __restrict__ part,
                                                    const int* __restrict__ bsum,
                                                    int* __restrict__ rowstart, int N, int Etot) {
    int i = blockIdx.x * 256 + threadIdx.x;
    if (i < N) rowstart[i] = part[i] + bsum[blockIdx.x];
    if (i == 0) rowstart[N] = Etot;
}

__global__ void fill_kernel(const int* __restrict__ ei, const int* __restrict__ rowstart,
                            int* __restrict__ cnt2, int* __restrict__ esrc, int E, int Etot) {
    int e = blockIdx.x * blockDim.x + threadIdx.x;
    if (e >= Etot) return;
    int s, d;
    if (e < E) { s = ei[e]; d = ei[E + e]; } else { s = e - E; d = s; }
    esrc[rowstart[d] + atomicAdd(&cnt2[d], 1)] = s;
}

// ---------------- bf16 conversion ----------------

__global__ void convX_kernel(const float* __restrict__ X, ushort_t* __restrict__ Xbf,
                             int N, long total) {
    long idx = (long)blockIdx.x * blockDim.x + threadIdx.x;
    if (idx >= total) return;
    int r = (int)(idx / KP), k = (int)(idx % KP);
    float v = (r < N && k < NUM_FEA) ? X[(long)r * NUM_FEA + k] : 0.f;
    Xbf[idx] = f2bf(v);
}

__global__ void convW_both_kernel(const float* __restrict__ W1, ushort_t* __restrict__ Wt1,
                                  const float* __restrict__ W2, ushort_t* __restrict__ Wt2) {
    int idx = blockIdx.x * blockDim.x + threadIdx.x;
    if (idx < F1 * KP) {
        int n = idx / KP, k = idx % KP;
        Wt1[idx] = (k < NUM_FEA) ? f2bf(W1[(long)k * F1 + n]) : (ushort_t)0;
    } else {
        int j = idx - F1 * KP;
        if (j < F2 * KP2) {
            int n = j / KP2, k = j % KP2;
            Wt2[j] = f2bf(W2[(long)k * F2 + n]);
        }
    }
}

// ---------------- GEMM1 via MFMA bf16 ----------------

__global__ __launch_bounds__(256) void gemm1_mfma(const ushort_t* __restrict__ Xbf,
                                                  const ushort_t* __restrict__ Wt,
                                                  ushort_t* __restrict__ Hout, int N) {
    __shared__ ushort_t As[MROWS * LDK];
    __shared__ ushort_t Bs[F1 * LDK];
    int tid = threadIdx.x;
    int wave = tid >> 6, lane = tid & 63;
    int q = lane >> 4, l16 = lane & 15;
    int wm = (wave >> 1) * 64;
    int wn = (wave & 1) * 96;
    long row0 = (long)blockIdx.x * MROWS;

    floatx4 acc[4][6] = {};

    for (int k0 = 0; k0 < KP; k0 += 32) {
#pragma unroll
        for (int p = 0; p < 2; p++) {
            int idx = p * 256 + tid;
            int r = idx >> 2, ks = (idx & 3) * 8;
            *(int4*)&As[r * LDK + ks] = *(const int4*)&Xbf[(row0 + r) * KP + k0 + ks];
        }
#pragma unroll
        for (int p = 0; p < 3; p++) {
            int idx = p * 256 + tid;
            int r = idx >> 2, ks = (idx & 3) * 8;
            *(int4*)&Bs[r * LDK + ks] = *(const int4*)&Wt[(long)r * KP + k0 + ks];
        }
        __syncthreads();
        bf16x8 af[4], bfr[6];
#pragma unroll
        for (int rt = 0; rt < 4; rt++)
            af[rt] = *(const bf16x8*)&As[(wm + rt * 16 + l16) * LDK + q * 8];
#pragma unroll
        for (int ct = 0; ct < 6; ct++)
            bfr[ct] = *(const bf16x8*)&Bs[(wn + ct * 16 + l16) * LDK + q * 8];
#pragma unroll
        for (int rt = 0; rt < 4; rt++)
#pragma unroll
            for (int ct = 0; ct < 6; ct++)
                acc[rt][ct] = __builtin_amdgcn_mfma_f32_16x16x32_bf16(af[rt], bfr[ct], acc[rt][ct], 0, 0, 0);
        __syncthreads();
    }
#pragma unroll
    for (int rt = 0; rt < 4; rt++) {
#pragma unroll
        for (int r = 0; r < 4; r++) {
            long grow = row0 + wm + rt * 16 + q * 4 + r;
            if (grow < N) {
#pragma unroll
                for (int ct = 0; ct < 6; ct++)
                    Hout[grow * F1 + wn + ct * 16 + l16] = f2bf(acc[rt][ct][r]);
            }
        }
    }
}

// ---------------- GEMM2 via MFMA bf16 ----------------

__global__ __launch_bounds__(256) void gemm2_mfma(const ushort_t* __restrict__ Xbf,
                                                  const ushort_t* __restrict__ Wt,
                                                  ushort_t* __restrict__ Hout, int N) {
    __shared__ ushort_t As[MROWS * LDK];
    __shared__ ushort_t Bs[F2 * LDK];
    int tid = threadIdx.x;
    int wave = tid >> 6, lane = tid & 63;
    int q = lane >> 4, l16 = lane & 15;
    int wm = (wave >> 1) * 64;
    int wn = (wave & 1) * 32;
    long row0 = (long)blockIdx.x * MROWS;

    floatx4 acc[4][2] = {};

    for (int k0 = 0; k0 < KP2; k0 += 32) {
#pragma unroll
        for (int p = 0; p < 2; p++) {
            int idx = p * 256 + tid;
            int r = idx >> 2, ks = (idx & 3) * 8;
            *(int4*)&As[r * LDK + ks] = *(const int4*)&Xbf[(row0 + r) * KP2 + k0 + ks];
        }
        {
            int r = tid >> 2, ks = (tid & 3) * 8;
            if (r < F2)
                *(int4*)&Bs[r * LDK + ks] = *(const int4*)&Wt[(long)r * KP2 + k0 + ks];
        }
        __syncthreads();
        bf16x8 af[4], bfr[2];
#pragma unroll
        for (int rt = 0; rt < 4; rt++)
            af[rt] = *(const bf16x8*)&As[(wm + rt * 16 + l16) * LDK + q * 8];
#pragma unroll
        for (int ct = 0; ct < 2; ct++)
            bfr[ct] = *(const bf16x8*)&Bs[(wn + ct * 16 + l16) * LDK + q * 8];
#pragma unroll
        for (int rt = 0; rt < 4; rt++)
#pragma unroll
            for (int ct = 0; ct < 2; ct++)
                acc[rt][ct] = __builtin_amdgcn_mfma_f32_16x16x32_bf16(af[rt], bfr[ct], acc[rt][ct], 0, 0, 0);
        __syncthreads();
    }
#pragma unroll
    for (int rt = 0; rt < 4; rt++) {
#pragma unroll
        for (int r = 0; r < 4; r++) {
            long grow = row0 + wm + rt * 16 + q * 4 + r;
            if (grow < N) {
#pragma unroll
                for (int ct = 0; ct < 2; ct++)
                    Hout[grow * F2 + wn + ct * 16 + l16] = f2bf(acc[rt][ct][r]);
            }
        }
    }
}

// ---------------- attention coefficients (bf16 h) ----------------

template<int H, int C>
__global__ void att_bf_kernel(const ushort_t* __restrict__ h, const float* __restrict__ att_s,
                              const float* __restrict__ att_d, float* __restrict__ as_,
                              float* __restrict__ ad_, int N) {
    int idx = blockIdx.x * blockDim.x + threadIdx.x;
    if (idx >= N * H) return;
    int n = idx / H, hd = idx % H;
    const ushort_t* hp = h + (long)n * H * C + hd * C;
    const float* sp = att_s + hd * C;
    const float* dp = att_d + hd * C;
    float ss = 0.f, dd = 0.f;
#pragma unroll
    for (int c = 0; c < C; c++) {
        float v = bf2f(hp[c]);
        ss += v * sp[c];
        dd += v * dp[c];
    }
    as_[idx] = ss;
    ad_[idx] = dd;
}

// ---------------- gather layer 1: one wave per node, 8B col loads ----------------
// lane j<48 owns cols 4j..4j+3 (all within head j>>2); 8-edge chunks.
// exp duties: duty0 = lane l -> (edge l/12, head l%12); duty1 = l+64 (l<32).

__global__ __launch_bounds__(256) void gather1_kernel(const int* __restrict__ rowstart,
                                                      const int* __restrict__ esrc,
                                                      const float* __restrict__ as_,
                                                      const float* __restrict__ ad_,
                                                      const ushort_t* __restrict__ h,
                                                      const float* __restrict__ bias,
                                                      ushort_t* __restrict__ xout, int N) {
    int d = blockIdx.x * 4 + (threadIdx.x >> 6);
    if (d >= N) return;
    int l = threadIdx.x & 63;
    int jc = l < 48 ? l : 47;         // clamped col-group (lanes 48-63 mirror lane 47)
    int hj = jc >> 2;                 // head of owned cols
    int e0 = l / 12, h0 = l - e0 * 12;
    int l64 = l + 64;
    int e1 = l64 / 12, h1 = l64 - e1 * 12;
    int beg = rowstart[d], end = rowstart[d + 1];
    float adv0 = ad_[d * NHEAD1 + h0];
    float adv1 = ad_[d * NHEAD1 + h1];
    float4 b4 = ((const float4*)bias)[jc];
    const ushort_t* hcol = h + 4 * jc;

    float acc0 = 0.f, acc1 = 0.f, acc2 = 0.f, acc3 = 0.f, accd = 0.f;

    for (int p = beg; p < end; p += 8) {
        int pp = p + (l & 7);
        int s_l = esrc[pp < end ? pp : beg];
        // broadcast edge source indices (lane i holds edge i)
        int s_e[8];
#pragma unroll
        for (int i = 0; i < 8; i++) s_e[i] = __shfl(s_l, i, 64);
        // issue the 8 independent 8-byte row loads
        uint2 g[8];
#pragma unroll
        for (int i = 0; i < 8; i++)
            g[i] = *(const uint2*)(hcol + (long)s_e[i] * F1);
        // dual exp duty
        int sq0 = __shfl(s_l, e0, 64);
        int sq1 = __shfl(s_l, e1, 64);
        float a0v = as_[sq0 * NHEAD1 + h0];
        float a1v = as_[sq1 * NHEAD1 + h1];
        float w0 = (p + e0 < end) ? __expf(lrelu(a0v + adv0)) : 0.f;
        float w1 = (e1 < 8 && p + e1 < end) ? __expf(lrelu(a1v + adv1)) : 0.f;
        // consume
#pragma unroll
        for (int i = 0; i < 8; i++) {
            float wi;
            if (i <= 4) {
                wi = __shfl(w0, i * 12 + hj, 64);
            } else if (i == 5) {
                float wa = __shfl(w0, 60 + hj, 64);
                int srcb = hj >= 4 ? hj - 4 : 0;
                float wb = __shfl(w1, srcb, 64);
                wi = (hj < 4) ? wa : wb;
            } else {
                wi = __shfl(w1, i * 12 + hj - 64, 64);
            }
            unsigned x = g[i].x, y = g[i].y;
            acc0 += wi * __uint_as_float(x << 16);
            acc1 += wi * __uint_as_float(x & 0xffff0000u);
            acc2 += wi * __uint_as_float(y << 16);
            acc3 += wi * __uint_as_float(y & 0xffff0000u);
            accd += wi;
        }
    }
    if (l < 48) {
        float v0 = elu(acc0 / accd + b4.x);
        float v1 = elu(acc1 / accd + b4.y);
        float v2 = elu(acc2 / accd + b4.z);
        float v3 = elu(acc3 / accd + b4.w);
        uint2 outp;
        outp.x = (unsigned)f2bf(v0) | ((unsigned)f2bf(v1) << 16);
        outp.y = (unsigned)f2bf(v2) | ((unsigned)f2bf(v3) << 16);
        *(uint2*)(xout + (long)d * F1 + 4 * l) = outp;
    }
}

// ---------------- gather layer 2: one wave/node, shuffle-deduped exp ----------------

__global__ __launch_bounds__(256) void gather2_kernel(const int* __restrict__ rowstart,
                                                      const int* __restrict__ esrc,
                                                      const float* __restrict__ as_,
                                                      const float* __restrict__ ad_,
                                                      const ushort_t* __restrict__ h,
                                                      const float* __restrict__ bias,
                                                      float* __restrict__ xout, int N) {
    int d = blockIdx.x * 4 + (threadIdx.x >> 6);
    if (d >= N) return;
    int lane = threadIdx.x & 63;
    int hd = lane >> 3;           // own head
    int ie = lane >> 3, hq = lane & 7;   // exp duty: edge ie, head hq
    int beg = rowstart[d], end = rowstart[d + 1];
    float advq = ad_[d * NHEAD2 + hq];
    const ushort_t* hp = h + lane;
    float accn = 0.f, accd = 0.f;
    for (int p = beg; p < end; p += 8) {
        int s[8];
        float g[8];
#pragma unroll
        for (int i = 0; i < 8; i++) {
            int pp = p + i;
            s[i] = esrc[pp < end ? pp : beg];
        }
#pragma unroll
        for (int i = 0; i < 8; i++)
            g[i] = bf2f(hp[(long)s[i] * F2]);
        int pe = p + ie;
        int sq = esrc[pe < end ? pe : beg];
        float aval = as_[sq * NHEAD2 + hq];
        float w = (pe < end) ? __expf(lrelu(aval + advq)) : 0.f;
#pragma unroll
        for (int i = 0; i < 8; i++) {
            float wi = __shfl(w, (i << 3) | hd, 64);
            accn += wi * g[i];
            accd += wi;
        }
    }
    float v = accn / accd + bias[lane];
    xout[(long)d * F2 + lane] = v > 0.f ? v : (__expf(v) - 1.f);
}

// ---------------- pair predictor ----------------

__global__ void pair_kernel(const float* __restrict__ x, const int* __restrict__ n1,
                            const int* __restrict__ n2, const float* __restrict__ linW,
                            const float* __restrict__ linb, float* __restrict__ y, int P) {
    int idx = blockIdx.x * blockDim.x + threadIdx.x;
    if (idx >= P) return;
    const float4* xa = (const float4*)(x + (long)n1[idx] * F2);
    const float4* xb = (const float4*)(x + (long)n2[idx] * F2);
    float a0 = linb[0], a1 = linb[1];
#pragma unroll
    for (int k4 = 0; k4 < F2 / 4; k4++) {
        float4 v = xa[k4];
        int k = k4 * 4;
        a0 += v.x * linW[2 * k] + v.y * linW[2 * (k + 1)] + v.z * linW[2 * (k + 2)] + v.w * linW[2 * (k + 3)];
        a1 += v.x * linW[2 * k + 1] + v.y * linW[2 * (k + 1) + 1] + v.z * linW[2 * (k + 2) + 1] + v.w * linW[2 * (k + 3) + 1];
    }
#pragma unroll
    for (int k4 = 0; k4 < F2 / 4; k4++) {
        float4 v = xb[k4];
        int k = F2 + k4 * 4;
        a0 += v.x * linW[2 * k] + v.y * linW[2 * (k + 1)] + v.z * linW[2 * (k + 2)] + v.w * linW[2 * (k + 3)];
        a1 += v.x * linW[2 * k + 1] + v.y * linW[2 * (k + 1) + 1] + v.z * linW[2 * (k + 2) + 1] + v.w * linW[2 * (k + 3) + 1];
    }
    y[2 * idx]     = 1.f / (1.f + __expf(-a0));
    y[2 * idx + 1] = 1.f / (1.f + __expf(-a1));
}

// ---------------- launch ----------------

extern "C" void kernel_launch(void* const* d_in, const int* in_sizes, int n_in,
                              void* d_out, int out_size, void* d_ws, size_t ws_size,
                              hipStream_t stream) {
    const float* features = (const float*)d_in[0];
    const int*   ei       = (const int*)d_in[1];
    const int*   n1       = (const int*)d_in[2];
    const int*   n2       = (const int*)d_in[3];
    const float* W1       = (const float*)d_in[4];
    const float* att_s1   = (const float*)d_in[5];
    const float* att_d1   = (const float*)d_in[6];
    const float* b1       = (const float*)d_in[7];
    const float* W2       = (const float*)d_in[8];
    const float* att_s2   = (const float*)d_in[9];
    const float* att_d2   = (const float*)d_in[10];
    const float* b2       = (const float*)d_in[11];
    const float* linW     = (const float*)d_in[12];
    const float* linb     = (const float*)d_in[13];

    const int N = in_sizes[0] / NUM_FEA;      // 50000
    const int E = in_sizes[1] / 2;            // 800000
    const int P = in_sizes[2];                // 16384
    const int Etot = E + N;                   // 850000

    const int nblk = (N + MROWS - 1) / MROWS;    // 391
    const int NPAD = nblk * MROWS;               // 50048
    const int nsb = (N + 255) / 256;             // scan blocks (196)

    float* ws = (float*)d_ws;
    long o = 0;
    float* h1r  = ws + o; o += (long)N * F1 / 2;             // h1b bf16
    float* xr   = ws + o; o += ((long)NPAD * KP + 1) / 2;    // Xbf then x1bf
    float* as1  = ws + o; o += (long)N * NHEAD1;
    float* ad1  = ws + o; o += (long)N * NHEAD1;
    float* h2r  = ws + o; o += (long)N * F2 / 2;             // h2b bf16
    float* as2  = ws + o; o += (long)N * NHEAD2;
    float* ad2  = ws + o; o += (long)N * NHEAD2;
    float* w1r  = ws + o; o += (F1 * KP + 1) / 2;            // Wt1 bf16
    float* w2r  = ws + o; o += (F2 * KP2 + 1) / 2;           // Wt2 bf16
    int* rowstart = (int*)(ws + o); o += N + 1;
    int* esrc = (int*)(ws + o); o += Etot;
    int* cnt  = (int*)(ws + o); o += N;
    int* cnt2 = (int*)(ws + o); o += N;
    int* part = (int*)(ws + o); o += N;
    int* bsum = (int*)(ws + o); o += 256;

    ushort_t* h1b  = (ushort_t*)h1r;
    ushort_t* Xbf  = (ushort_t*)xr;
    ushort_t* x1bf = (ushort_t*)xr;    // after Xbf dead
    ushort_t* h2b  = (ushort_t*)h2r;
    ushort_t* Wt1  = (ushort_t*)w1r;
    ushort_t* Wt2  = (ushort_t*)w2r;

    float* y_out = (float*)d_out;
    float* x_out = (float*)d_out + (long)2 * P;

    hipMemsetAsync(cnt, 0, (size_t)2 * N * sizeof(int), stream);

    // CSR build
    deg_kernel<<<(Etot + 255) / 256, 256, 0, stream>>>(ei, cnt, E, Etot);
    scan1_kernel<<<nsb, 256, 0, stream>>>(cnt, part, bsum, N);
    scan2_kernel<<<1, 256, 0, stream>>>(bsum, nsb);
    scan3_kernel<<<nsb, 256, 0, stream>>>(part, bsum, rowstart, N, Etot);
    fill_kernel<<<(Etot + 255) / 256, 256, 0, stream>>>(ei, rowstart, cnt2, esrc, E, Etot);

    // weight prep (independent of CSR)
    convW_both_kernel<<<(F1 * KP + F2 * KP2 + 255) / 256, 256, 0, stream>>>(W1, Wt1, W2, Wt2);

    // layer 1
    long totX = (long)NPAD * KP;
    convX_kernel<<<(int)((totX + 255) / 256), 256, 0, stream>>>(features, Xbf, N, totX);
    gemm1_mfma<<<nblk, 256, 0, stream>>>(Xbf, Wt1, h1b, N);
    att_bf_kernel<NHEAD1, HID1><<<(N * NHEAD1 + 255) / 256, 256, 0, stream>>>(h1b, att_s1, att_d1, as1, ad1, N);
    gather1_kernel<<<(N + 3) / 4, 256, 0, stream>>>(rowstart, esrc, as1, ad1, h1b, b1, x1bf, N);

    // layer 2
    gemm2_mfma<<<nblk, 256, 0, stream>>>(x1bf, Wt2, h2b, N);
    att_bf_kernel<NHEAD2, HID2><<<(N * NHEAD2 + 255) / 256, 256, 0, stream>>>(h2b, att_s2, att_d2, as2, ad2, N);
    gather2_kernel<<<(N + 3) / 4, 256, 0, stream>>>(rowstart, esrc, as2, ad2, h2b, b2, x_out, N);

    // pair predictor
    pair_kernel<<<(P + 255) / 256, 256, 0, stream>>>(x_out, n1, n2, linW, linb, y_out, P);
}